// Round 11
// baseline (62.264 us; speedup 1.0000x reference)
//
#include <hip/hip_runtime.h>
#include <math.h>

#define B_ 16
#define L_ 1024
#define IMG 224
#define PIX (IMG*IMG)        /* 50176 */
#define NBD 128
#define NRES 512             /* resize blocks in K2 */

/* ---- workspace (float words) ----
   OFF_A    : a[128]        OFF_TERM : term[128]
   OFF_GPMIN: partials[512] OFF_GPMAX: partials[512]
   OFF_CTR  : completion counter (uint view), reset by K1 every call
   OFF_T    : tbl[16][224][16]   OFF_G : g[16][224][224]
*/
#define OFF_A     0
#define OFF_TERM  128
#define OFF_GPMIN 256
#define OFF_GPMAX 768
#define OFF_CTR   1280
#define OFF_T     1284                 /* 57344 floats, 16B-aligned */
#define OFF_G     58628                /* 802816 floats, 16B-aligned */

#define CPAD(k) ((((k) >> 4) * 17) + ((k) & 15))

__device__ __forceinline__ float cclip(float xn) {
    return fminf(fmaxf(xn, -1.0f + 1e-6f), 1.0f - 1e-6f);
}
__device__ __forceinline__ int bucketf(float c) {
    int k = (int)((c + 1.0f) * 512.0f);
    return min(1023, max(0, k));
}

template <int NTHR>
__device__ __forceinline__ void block_minmax_share(float mn, float mx, float* red) {
    #pragma unroll
    for (int off = 32; off > 0; off >>= 1) {
        mn = fminf(mn, __shfl_down(mn, off));
        mx = fmaxf(mx, __shfl_down(mx, off));
    }
    const int lane = threadIdx.x & 63;
    const int wave = threadIdx.x >> 6;
    if (lane == 0) { red[2 + wave*2] = mn; red[3 + wave*2] = mx; }
    __syncthreads();
    if (threadIdx.x == 0) {
        #pragma unroll
        for (int w = 1; w < NTHR/64; ++w) {
            mn = fminf(mn, red[2 + w*2]);
            mx = fmaxf(mx, red[3 + w*2]);
        }
        red[0] = mn; red[1] = mx;
    }
    __syncthreads();
}

/* K1: one block per (b,d), 1024 threads — identical to R9's k_bd, plus a
   one-word counter reset (stream-prior, so K2 always sees 0). */
__global__ __launch_bounds__(1024) void k_bd(const float* __restrict__ x,
                                             float* __restrict__ wsf,
                                             unsigned* __restrict__ wsu) {
    __shared__ float red[36];
    __shared__ float corig[L_];
    __shared__ float arr[L_];
    __shared__ int   cnt[1090];
    __shared__ int   pref[1090];
    const int bd = blockIdx.x;
    const int b = bd >> 3, d = bd & 7;
    const int t = threadIdx.x;

    if (bd == 0 && t == 0) wsu[OFF_CTR] = 0u;   /* reset for this call */

    /* (a) global x min/max, redundant per block */
    {
        float mn = 1e30f, mx = -1e30f;
        const float4* xv = (const float4*)x;
        #pragma unroll 4
        for (int i = t; i < 32768; i += 1024) {
            float4 v = xv[i];
            mn = fminf(mn, fminf(fminf(v.x, v.y), fminf(v.z, v.w)));
            mx = fmaxf(mx, fmaxf(fmaxf(v.x, v.y), fmaxf(v.z, v.w)));
        }
        block_minmax_share<1024>(mn, mx, red);
    }
    float lo = red[0], hi = red[1], r = hi - lo, sc, sh;
    if (r < 1e-8f) { sc = 0.0f; sh = -1.0f; }
    else           { sc = 2.0f / (r + 1e-8f); sh = -lo*sc - 1.0f; }

    /* (b) load row (1/thread), zero counts */
    cnt[t] = 0;
    if (t < 66) cnt[1024 + t] = 0;
    float c = cclip(x[((size_t)(b*L_ + t))*8 + d]*sc + sh);
    corig[t] = c;
    block_minmax_share<1024>(c, c, red);
    float cMin = red[0], cMax = red[1];

    atomicAdd(&cnt[CPAD(bucketf(c))], 1);
    __syncthreads();

    if (t < 64) {
        int s = 0;
        #pragma unroll
        for (int e = 0; e < 16; ++e) s += cnt[t*17 + e];
        int v = s;
        #pragma unroll
        for (int o = 1; o < 64; o <<= 1) {
            int u = __shfl_up(v, o);
            if (t >= o) v += u;
        }
        int run = v - s;
        #pragma unroll
        for (int e = 0; e < 16; ++e) { pref[t*17 + e] = run; run += cnt[t*17 + e]; }
        if (t == 63) pref[CPAD(1024)] = run;
    }
    __syncthreads();
    cnt[CPAD(t)] = pref[CPAD(t)];
    __syncthreads();
    {
        int p = atomicAdd(&cnt[CPAD(bucketf(c))], 1);
        arr[p] = c;
    }
    __syncthreads();

    /* (c) pair-min via neighbor span of -c_i */
    float rowmin = 1e30f;
    {
        float ci = c;
        float si = sqrtf(fmaxf(1.0f - ci*ci, 0.0f));
        int kt = bucketf(-ci);
        int lo_p = pref[CPAD(kt)], hi_p = pref[CPAD(kt + 1)];
        int start = lo_p, end = hi_p;
        if (lo_p > 0)   start = pref[CPAD(bucketf(arr[lo_p - 1]))];
        if (hi_p < L_)  end   = pref[CPAD(bucketf(arr[hi_p]) + 1)];
        for (int p = start; p < end; ++p) {
            float cj = arr[p];
            float sj = sqrtf(fmaxf(1.0f - cj*cj, 0.0f));
            rowmin = fminf(rowmin, ci*cj - si*sj);
        }
    }
    block_minmax_share<1024>(rowmin, -1e30f, red);
    if (t == 0) {
        float plo = red[0];
        float phi = fmaxf(2.0f*cMin*cMin - 1.0f, 2.0f*cMax*cMax - 1.0f);
        float rr  = phi - plo;
        float inv = (rr < 1e-8f) ? 0.0f : 1.0f / (rr + 1e-8f);
        wsf[OFF_A + bd]    = inv * 0.125f;
        wsf[OFF_TERM + bd] = plo * inv * 0.125f;
    }

    /* (e) sample table d-slice */
    if (t < IMG) {
        const float SC = 1024.0f / 224.0f;
        float syf = (t + 0.5f)*SC - 0.5f;
        int i0 = (int)floorf(syf);
        i0 = max(0, min(i0, L_ - 2));
        float f = syf - (float)i0;
        float ca = corig[i0], cb = corig[i0 + 1];
        float sa = sqrtf(fmaxf(1.0f - ca*ca, 0.0f));
        float sb = sqrtf(fmaxf(1.0f - cb*cb, 0.0f));
        size_t base = OFF_T + ((size_t)(b*IMG + t))*16;
        wsf[base + d]     = ca + f*(cb - ca);
        wsf[base + 8 + d] = sa + f*(sb - sa);
    }
}

/* K2: blocks [0,512) = resize (R9 k_resize + release-counter);
       blocks [512,1296) = out (spin-acquire + R9 k_out).
   All 1296x256 co-resident (<= 2048 block slots) => no deadlock. */
__global__ __launch_bounds__(256) void k_fused(float* __restrict__ wsf,
                                               unsigned* __restrict__ wsu,
                                               float* __restrict__ out) {
    __shared__ float red[16];
    const int t = threadIdx.x;

    if (blockIdx.x < NRES) {
        /* ---------------- resize role ---------------- */
        __shared__ float lds_y[112];
        int b     = blockIdx.x >> 5;
        int strip = blockIdx.x & 31;
        const float* tb = wsf + OFF_T + (size_t)b*IMG*16;
        if (t < 112) lds_y[t] = tb[strip*112 + t];
        __syncthreads();
        int ox = min(t, IMG-1);
        bool active = (t < IMG);
        const float4* xt = (const float4*)(tb + (size_t)ox*16);
        float4 cx0 = xt[0], cx1 = xt[1], sx0 = xt[2], sx1 = xt[3];
        const float4* av = (const float4*)(wsf + OFF_A + b*8);
        float4 a0 = av[0], a1 = av[1];
        float bias = 0.f;
        #pragma unroll
        for (int dd = 0; dd < 8; ++dd) bias += wsf[OFF_TERM + b*8 + dd];
        float mn = 1e30f, mx = -1e30f;
        #pragma unroll
        for (int rr = 0; rr < 7; ++rr) {
            const float* Y = lds_y + rr*16;
            float acc;
            acc  = (a0.x*Y[0])*cx0.x - (a0.x*Y[ 8])*sx0.x;
            acc += (a0.y*Y[1])*cx0.y - (a0.y*Y[ 9])*sx0.y;
            acc += (a0.z*Y[2])*cx0.z - (a0.z*Y[10])*sx0.z;
            acc += (a0.w*Y[3])*cx0.w - (a0.w*Y[11])*sx0.w;
            acc += (a1.x*Y[4])*cx1.x - (a1.x*Y[12])*sx1.x;
            acc += (a1.y*Y[5])*cx1.y - (a1.y*Y[13])*sx1.y;
            acc += (a1.z*Y[6])*cx1.z - (a1.z*Y[14])*sx1.z;
            acc += (a1.w*Y[7])*cx1.w - (a1.w*Y[15])*sx1.w;
            float g = acc - bias;
            if (active) {
                int oy = strip*7 + rr;
                wsf[OFF_G + ((size_t)(b*IMG + oy))*IMG + ox] = g;
                mn = fminf(mn, g);
                mx = fmaxf(mx, g);
            }
        }
        block_minmax_share<256>(mn, mx, red);
        if (t == 0) {
            wsf[OFF_GPMIN + blockIdx.x] = red[0];
            wsf[OFF_GPMAX + blockIdx.x] = red[1];
            /* release: makes g + partials agent-visible, then count up */
            __hip_atomic_fetch_add(&wsu[OFF_CTR], 1u,
                                   __ATOMIC_RELEASE, __HIP_MEMORY_SCOPE_AGENT);
        }
    } else {
        /* ---------------- out role ---------------- */
        if (t == 0) {
            while (__hip_atomic_load(&wsu[OFF_CTR], __ATOMIC_RELAXED,
                                     __HIP_MEMORY_SCOPE_AGENT) < (unsigned)NRES)
                __builtin_amdgcn_s_sleep(2);
            (void)__hip_atomic_load(&wsu[OFF_CTR], __ATOMIC_ACQUIRE,
                                    __HIP_MEMORY_SCOPE_AGENT);
        }
        __syncthreads();
        float pmn = fminf(wsf[OFF_GPMIN + t], wsf[OFF_GPMIN + t + 256]);
        float pmx = fmaxf(wsf[OFF_GPMAX + t], wsf[OFF_GPMAX + t + 256]);
        block_minmax_share<256>(pmn, pmx, red);
        float gmin = red[0];
        float scale = 1.0f / ((red[1] - gmin) + 1e-6f);
        int idx = (blockIdx.x - NRES)*256 + t;       /* [0, 200704) float4 */
        float4 gv = ((const float4*)(wsf + OFF_G))[idx];
        float4 v;
        v.x = (gv.x - gmin)*scale;
        v.y = (gv.y - gmin)*scale;
        v.z = (gv.z - gmin)*scale;
        v.w = (gv.w - gmin)*scale;
        int b   = idx / (PIX/4);
        int rem = idx - b*(PIX/4);
        float4* ob = (float4*)(out + (size_t)b*3*PIX) + rem;
        ob[0]         = v;
        ob[PIX/4]     = v;
        ob[2*(PIX/4)] = v;
    }
}

extern "C" void kernel_launch(void* const* d_in, const int* in_sizes, int n_in,
                              void* d_out, int out_size, void* d_ws, size_t ws_size,
                              hipStream_t stream) {
    const float* x = (const float*)d_in[0];
    float* out     = (float*)d_out;
    float* wsf     = (float*)d_ws;
    unsigned* wsu  = (unsigned*)d_ws;

    k_bd   <<<NBD,                    1024, 0, stream>>>(x, wsf, wsu);
    k_fused<<<NRES + (B_*PIX/4)/256,  256,  0, stream>>>(wsf, wsu, out);
}

// Round 12
// 33.679 us; speedup vs baseline: 1.8487x; 1.8487x over previous
//
#include <hip/hip_runtime.h>
#include <math.h>

#define B_ 16
#define L_ 1024
#define IMG 224
#define PIX (IMG*IMG)        /* 50176 */
#define NBD 128

/* ---- workspace (float) layout — plain stores only, no atomics, no init ----
   OFF_A    : a[128]    = inv/8 per (b,d)
   OFF_TERM : term[128] = lo*inv/8 per (b,d)
   OFF_GPMIN: g min partials[512]   OFF_GPMAX: g max partials[512]
   OFF_T    : tbl[B][224][16]  (lerped c[0..7], s[0..7] at sample positions)
*/
#define OFF_A     0
#define OFF_TERM  128
#define OFF_GPMIN 256
#define OFF_GPMAX 768
#define OFF_T     1280                 /* 57344 floats */

#define CPAD(k) ((((k) >> 4) * 17) + ((k) & 15))

__device__ __forceinline__ float cclip(float xn) {
    return fminf(fmaxf(xn, -1.0f + 1e-6f), 1.0f - 1e-6f);
}
__device__ __forceinline__ int bucketf(float c) {
    int k = (int)((c + 1.0f) * 512.0f);
    return min(1023, max(0, k));
}

template <int NTHR>
__device__ __forceinline__ void block_minmax_share(float mn, float mx, float* red) {
    #pragma unroll
    for (int off = 32; off > 0; off >>= 1) {
        mn = fminf(mn, __shfl_down(mn, off));
        mx = fmaxf(mx, __shfl_down(mx, off));
    }
    const int lane = threadIdx.x & 63;
    const int wave = threadIdx.x >> 6;
    if (lane == 0) { red[2 + wave*2] = mn; red[3 + wave*2] = mx; }
    __syncthreads();
    if (threadIdx.x == 0) {
        #pragma unroll
        for (int w = 1; w < NTHR/64; ++w) {
            mn = fminf(mn, red[2 + w*2]);
            mx = fmaxf(mx, red[3 + w*2]);
        }
        red[0] = mn; red[1] = mx;
    }
    __syncthreads();
}

/* K1: one block per (b,d), 1024 threads — R9's proven kernel, unchanged. */
__global__ __launch_bounds__(1024) void k_bd(const float* __restrict__ x,
                                             float* __restrict__ wsf) {
    __shared__ float red[36];
    __shared__ float corig[L_];
    __shared__ float arr[L_];
    __shared__ int   cnt[1090];
    __shared__ int   pref[1090];
    const int bd = blockIdx.x;
    const int b = bd >> 3, d = bd & 7;
    const int t = threadIdx.x;

    /* (a) global x min/max, redundant per block (L2-resident, identical) */
    {
        float mn = 1e30f, mx = -1e30f;
        const float4* xv = (const float4*)x;
        #pragma unroll 4
        for (int i = t; i < 32768; i += 1024) {
            float4 v = xv[i];
            mn = fminf(mn, fminf(fminf(v.x, v.y), fminf(v.z, v.w)));
            mx = fmaxf(mx, fmaxf(fmaxf(v.x, v.y), fmaxf(v.z, v.w)));
        }
        block_minmax_share<1024>(mn, mx, red);
    }
    float lo = red[0], hi = red[1], r = hi - lo, sc, sh;
    if (r < 1e-8f) { sc = 0.0f; sh = -1.0f; }
    else           { sc = 2.0f / (r + 1e-8f); sh = -lo*sc - 1.0f; }

    /* (b) load row (1/thread), zero counts */
    cnt[t] = 0;
    if (t < 66) cnt[1024 + t] = 0;
    float c = cclip(x[((size_t)(b*L_ + t))*8 + d]*sc + sh);
    corig[t] = c;
    block_minmax_share<1024>(c, c, red);
    float cMin = red[0], cMax = red[1];

    atomicAdd(&cnt[CPAD(bucketf(c))], 1);
    __syncthreads();

    if (t < 64) {
        int s = 0;
        #pragma unroll
        for (int e = 0; e < 16; ++e) s += cnt[t*17 + e];
        int v = s;
        #pragma unroll
        for (int o = 1; o < 64; o <<= 1) {
            int u = __shfl_up(v, o);
            if (t >= o) v += u;
        }
        int run = v - s;
        #pragma unroll
        for (int e = 0; e < 16; ++e) { pref[t*17 + e] = run; run += cnt[t*17 + e]; }
        if (t == 63) pref[CPAD(1024)] = run;
    }
    __syncthreads();
    cnt[CPAD(t)] = pref[CPAD(t)];
    __syncthreads();
    {
        int p = atomicAdd(&cnt[CPAD(bucketf(c))], 1);
        arr[p] = c;
    }
    __syncthreads();

    /* (c) pair-min via neighbor span of -c_i */
    float rowmin = 1e30f;
    {
        float ci = c;
        float si = sqrtf(fmaxf(1.0f - ci*ci, 0.0f));
        int kt = bucketf(-ci);
        int lo_p = pref[CPAD(kt)], hi_p = pref[CPAD(kt + 1)];
        int start = lo_p, end = hi_p;
        if (lo_p > 0)   start = pref[CPAD(bucketf(arr[lo_p - 1]))];
        if (hi_p < L_)  end   = pref[CPAD(bucketf(arr[hi_p]) + 1)];
        for (int p = start; p < end; ++p) {
            float cj = arr[p];
            float sj = sqrtf(fmaxf(1.0f - cj*cj, 0.0f));
            rowmin = fminf(rowmin, ci*cj - si*sj);
        }
    }
    block_minmax_share<1024>(rowmin, -1e30f, red);
    if (t == 0) {
        float plo = red[0];
        float phi = fmaxf(2.0f*cMin*cMin - 1.0f, 2.0f*cMax*cMax - 1.0f);
        float rr  = phi - plo;
        float inv = (rr < 1e-8f) ? 0.0f : 1.0f / (rr + 1e-8f);
        wsf[OFF_A + bd]    = inv * 0.125f;
        wsf[OFF_TERM + bd] = plo * inv * 0.125f;
    }

    /* (e) sample table d-slice */
    if (t < IMG) {
        const float SC = 1024.0f / 224.0f;
        float syf = (t + 0.5f)*SC - 0.5f;
        int i0 = (int)floorf(syf);
        i0 = max(0, min(i0, L_ - 2));
        float f = syf - (float)i0;
        float ca = corig[i0], cb = corig[i0 + 1];
        float sa = sqrtf(fmaxf(1.0f - ca*ca, 0.0f));
        float sb = sqrtf(fmaxf(1.0f - cb*cb, 0.0f));
        size_t base = OFF_T + ((size_t)(b*IMG + t))*16;
        wsf[base + d]     = ca + f*(cb - ca);
        wsf[base + 8 + d] = sa + f*(sb - sa);
    }
}

/* shared inner product: g(oy,ox) — identical expression order in K2 and K3
   so the min/max and the written values are bit-identical. */
__device__ __forceinline__ float g_eval(const float* __restrict__ Y,
                                        float4 cx0, float4 cx1,
                                        float4 sx0, float4 sx1,
                                        float4 a0, float4 a1, float bias) {
    float acc;
    acc  = (a0.x*Y[0])*cx0.x - (a0.x*Y[ 8])*sx0.x;
    acc += (a0.y*Y[1])*cx0.y - (a0.y*Y[ 9])*sx0.y;
    acc += (a0.z*Y[2])*cx0.z - (a0.z*Y[10])*sx0.z;
    acc += (a0.w*Y[3])*cx0.w - (a0.w*Y[11])*sx0.w;
    acc += (a1.x*Y[4])*cx1.x - (a1.x*Y[12])*sx1.x;
    acc += (a1.y*Y[5])*cx1.y - (a1.y*Y[13])*sx1.y;
    acc += (a1.z*Y[6])*cx1.z - (a1.z*Y[14])*sx1.z;
    acc += (a1.w*Y[7])*cx1.w - (a1.w*Y[15])*sx1.w;
    return acc - bias;
}

/* K2: g min/max only (no g store). 512 blocks = 16 b x 32 strips of 7 rows. */
__global__ __launch_bounds__(256) void k_gminmax(float* __restrict__ wsf) {
    __shared__ float lds_y[112];
    __shared__ float red[16];
    int b     = blockIdx.x >> 5;
    int strip = blockIdx.x & 31;
    const float* tb = wsf + OFF_T + (size_t)b*IMG*16;
    int t = threadIdx.x;
    if (t < 112) lds_y[t] = tb[strip*112 + t];
    __syncthreads();
    int ox = min(t, IMG-1);
    bool active = (t < IMG);
    const float4* xt = (const float4*)(tb + (size_t)ox*16);
    float4 cx0 = xt[0], cx1 = xt[1], sx0 = xt[2], sx1 = xt[3];
    const float4* av = (const float4*)(wsf + OFF_A + b*8);
    float4 a0 = av[0], a1 = av[1];
    float bias = 0.f;
    #pragma unroll
    for (int dd = 0; dd < 8; ++dd) bias += wsf[OFF_TERM + b*8 + dd];
    float mn = 1e30f, mx = -1e30f;
    #pragma unroll
    for (int rr = 0; rr < 7; ++rr) {
        float g = g_eval(lds_y + rr*16, cx0, cx1, sx0, sx1, a0, a1, bias);
        if (active) { mn = fminf(mn, g); mx = fmaxf(mx, g); }
    }
    block_minmax_share<256>(mn, mx, red);
    if (t == 0) {
        wsf[OFF_GPMIN + blockIdx.x] = red[0];
        wsf[OFF_GPMAX + blockIdx.x] = red[1];
    }
}

/* K3: reduce 512 partials, recompute g from tables (bit-identical), write
   3 channels. 784 blocks x 256 thr; thread = one float4 group (4 ox). */
__global__ __launch_bounds__(256) void k_out(const float* __restrict__ wsf,
                                             float* __restrict__ out) {
    __shared__ float red[16];
    int t = threadIdx.x;
    float pmn = fminf(wsf[OFF_GPMIN + t], wsf[OFF_GPMIN + t + 256]);
    float pmx = fmaxf(wsf[OFF_GPMAX + t], wsf[OFF_GPMAX + t + 256]);
    block_minmax_share<256>(pmn, pmx, red);
    float gmin = red[0];
    float scale = 1.0f / ((red[1] - gmin) + 1e-6f);

    int idx = blockIdx.x*256 + t;                /* [0, 200704) float4 groups */
    int b   = idx / (PIX/4);
    int rem = idx - b*(PIX/4);
    int oy  = rem / 56;                          /* 224/4 = 56 groups/row */
    int gx  = rem - oy*56;
    int ox0 = gx*4;

    const float* tb = wsf + OFF_T + (size_t)b*IMG*16;
    const float* Y  = tb + (size_t)oy*16;
    const float4* av = (const float4*)(wsf + OFF_A + b*8);
    float4 a0 = av[0], a1 = av[1];
    float bias = 0.f;
    #pragma unroll
    for (int dd = 0; dd < 8; ++dd) bias += wsf[OFF_TERM + b*8 + dd];

    float4 v;
    #pragma unroll
    for (int j = 0; j < 4; ++j) {
        const float4* xt = (const float4*)(tb + (size_t)(ox0 + j)*16);
        float4 cx0 = xt[0], cx1 = xt[1], sx0 = xt[2], sx1 = xt[3];
        float g = g_eval(Y, cx0, cx1, sx0, sx1, a0, a1, bias);
        (&v.x)[j] = (g - gmin)*scale;
    }
    float4* ob = (float4*)(out + (size_t)b*3*PIX) + rem;
    ob[0]         = v;
    ob[PIX/4]     = v;
    ob[2*(PIX/4)] = v;
}

extern "C" void kernel_launch(void* const* d_in, const int* in_sizes, int n_in,
                              void* d_out, int out_size, void* d_ws, size_t ws_size,
                              hipStream_t stream) {
    const float* x = (const float*)d_in[0];
    float* out     = (float*)d_out;
    float* wsf     = (float*)d_ws;

    k_bd     <<<NBD,            1024, 0, stream>>>(x, wsf);
    k_gminmax<<<512,            256,  0, stream>>>(wsf);
    k_out    <<<(B_*PIX/4)/256, 256,  0, stream>>>(wsf, out);
}

// Round 13
// 28.103 us; speedup vs baseline: 2.2155x; 1.1984x over previous
//
#include <hip/hip_runtime.h>
#include <math.h>

#define B_ 16
#define L_ 1024
#define IMG 224
#define PIX (IMG*IMG)        /* 50176 */
#define NBD 128

/* ---- workspace (float) layout — plain stores only, no atomics, no init ----
   OFF_A    : a[128]    = inv/8 per (b,d)
   OFF_TERM : term[128] = lo*inv/8 per (b,d)
   OFF_GPMIN: g min partials[512]   OFF_GPMAX: g max partials[512]
   OFF_T    : tbl[B][224][16]  (lerped c[0..7], s[0..7] at sample positions)
   OFF_G    : g[B][224][224]
*/
#define OFF_A     0
#define OFF_TERM  128
#define OFF_GPMIN 256
#define OFF_GPMAX 768
#define OFF_T     1280                 /* 57344 floats */
#define OFF_G     58624                /* 802816 floats */

/* pad-17 bucket layout: bucket k -> slot (k>>4)*17 + (k&15).
   scan reads stride-17 (all banks, gcd(17,32)=1); adjacent buckets ->
   adjacent banks for the data-dependent count atomics. */
#define CPAD(k) ((((k) >> 4) * 17) + ((k) & 15))

__device__ __forceinline__ float cclip(float xn) {
    return fminf(fmaxf(xn, -1.0f + 1e-6f), 1.0f - 1e-6f);
}
__device__ __forceinline__ int bucketf(float c) {
    int k = (int)((c + 1.0f) * 512.0f);
    return min(1023, max(0, k));
}

template <int NTHR>
__device__ __forceinline__ void block_minmax_share(float mn, float mx, float* red) {
    #pragma unroll
    for (int off = 32; off > 0; off >>= 1) {
        mn = fminf(mn, __shfl_down(mn, off));
        mx = fmaxf(mx, __shfl_down(mx, off));
    }
    const int lane = threadIdx.x & 63;
    const int wave = threadIdx.x >> 6;
    if (lane == 0) { red[2 + wave*2] = mn; red[3 + wave*2] = mx; }
    __syncthreads();
    if (threadIdx.x == 0) {
        #pragma unroll
        for (int w = 1; w < NTHR/64; ++w) {
            mn = fminf(mn, red[2 + w*2]);
            mx = fmaxf(mx, red[3 + w*2]);
        }
        red[0] = mn; red[1] = mx;
    }
    __syncthreads();
}

/* K1: one block per (b,d), 1024 threads (1 row each).
   (a) redundant global x min/max (x is L2-resident; identical per block)
   (b) bucket counting-sort (pad-17, conflict-free scan)
   (c) analytic pair min/max:
         max = max(2*cmin^2-1, 2*cmax^2-1)
         min = min over i of exact cos at the c-neighbors of -c_i
   (d) a[bd], term[bd]; (e) d-slice of the (c,s) sample table. */
__global__ __launch_bounds__(1024) void k_bd(const float* __restrict__ x,
                                             float* __restrict__ wsf) {
    __shared__ float red[36];
    __shared__ float corig[L_];
    __shared__ float arr[L_];
    __shared__ int   cnt[1090];        /* counts, then scatter cursors */
    __shared__ int   pref[1090];
    const int bd = blockIdx.x;
    const int b = bd >> 3, d = bd & 7;
    const int t = threadIdx.x;

    /* (a) global x min/max */
    {
        float mn = 1e30f, mx = -1e30f;
        const float4* xv = (const float4*)x;
        #pragma unroll 4
        for (int i = t; i < 32768; i += 1024) {
            float4 v = xv[i];
            mn = fminf(mn, fminf(fminf(v.x, v.y), fminf(v.z, v.w)));
            mx = fmaxf(mx, fmaxf(fmaxf(v.x, v.y), fmaxf(v.z, v.w)));
        }
        block_minmax_share<1024>(mn, mx, red);
    }
    float lo = red[0], hi = red[1], r = hi - lo, sc, sh;
    if (r < 1e-8f) { sc = 0.0f; sh = -1.0f; }
    else           { sc = 2.0f / (r + 1e-8f); sh = -lo*sc - 1.0f; }

    /* (b) load row (1/thread), zero counts */
    cnt[t] = 0;
    if (t < 66) cnt[1024 + t] = 0;
    float c = cclip(x[((size_t)(b*L_ + t))*8 + d]*sc + sh);
    corig[t] = c;
    block_minmax_share<1024>(c, c, red);      /* also orders cnt/corig */
    float cMin = red[0], cMax = red[1];

    /* count */
    atomicAdd(&cnt[CPAD(bucketf(c))], 1);
    __syncthreads();

    /* exclusive prefix over 1024 buckets: wave 0, 16 buckets/lane,
       pad-17 -> conflict-free reads/writes */
    if (t < 64) {
        int s = 0;
        #pragma unroll
        for (int e = 0; e < 16; ++e) s += cnt[t*17 + e];
        int v = s;
        #pragma unroll
        for (int o = 1; o < 64; o <<= 1) {
            int u = __shfl_up(v, o);
            if (t >= o) v += u;
        }
        int run = v - s;                      /* exclusive chunk prefix */
        #pragma unroll
        for (int e = 0; e < 16; ++e) { pref[t*17 + e] = run; run += cnt[t*17 + e]; }
        if (t == 63) pref[CPAD(1024)] = run;
    }
    __syncthreads();
    cnt[CPAD(t)] = pref[CPAD(t)];             /* cursors, bucket t */
    __syncthreads();
    /* scatter */
    {
        int p = atomicAdd(&cnt[CPAD(bucketf(c))], 1);
        arr[p] = c;
    }
    __syncthreads();

    /* (c) pair-min via neighbor span of -c_i (1 target/thread) */
    float rowmin = 1e30f;
    {
        float ci = c;
        float si = sqrtf(fmaxf(1.0f - ci*ci, 0.0f));
        int kt = bucketf(-ci);
        int lo_p = pref[CPAD(kt)], hi_p = pref[CPAD(kt + 1)];
        int start = lo_p, end = hi_p;
        if (lo_p > 0)   start = pref[CPAD(bucketf(arr[lo_p - 1]))];
        if (hi_p < L_)  end   = pref[CPAD(bucketf(arr[hi_p]) + 1)];
        for (int p = start; p < end; ++p) {
            float cj = arr[p];
            float sj = sqrtf(fmaxf(1.0f - cj*cj, 0.0f));
            rowmin = fminf(rowmin, ci*cj - si*sj);
        }
    }
    block_minmax_share<1024>(rowmin, -1e30f, red);
    if (t == 0) {
        float plo = red[0];
        float phi = fmaxf(2.0f*cMin*cMin - 1.0f, 2.0f*cMax*cMax - 1.0f);
        float rr  = phi - plo;
        float inv = (rr < 1e-8f) ? 0.0f : 1.0f / (rr + 1e-8f);
        wsf[OFF_A + bd]    = inv * 0.125f;
        wsf[OFF_TERM + bd] = plo * inv * 0.125f;
    }

    /* (e) sample table d-slice: lerped (c,s) at 224 half-pixel positions */
    if (t < IMG) {
        const float SC = 1024.0f / 224.0f;
        float syf = (t + 0.5f)*SC - 0.5f;
        int i0 = (int)floorf(syf);
        i0 = max(0, min(i0, L_ - 2));
        float f = syf - (float)i0;
        float ca = corig[i0], cb = corig[i0 + 1];
        float sa = sqrtf(fmaxf(1.0f - ca*ca, 0.0f));
        float sb = sqrtf(fmaxf(1.0f - cb*cb, 0.0f));
        size_t base = OFF_T + ((size_t)(b*IMG + t))*16;
        wsf[base + d]     = ca + f*(cb - ca);
        wsf[base + 8 + d] = sa + f*(sb - sa);
    }
}

/* K2: resize. 512 blocks = 16 b x 32 strips of 7 rows; thread = ox.
   x-side (c,s) coalesced from table, y-side via 112-float LDS strip.
   g min/max per block -> plain-store partials. */
__global__ __launch_bounds__(256) void k_resize(float* __restrict__ wsf) {
    __shared__ float lds_y[112];
    __shared__ float red[16];
    int b     = blockIdx.x >> 5;
    int strip = blockIdx.x & 31;
    const float* tb = wsf + OFF_T + (size_t)b*IMG*16;
    int t = threadIdx.x;
    if (t < 112) lds_y[t] = tb[strip*112 + t];
    __syncthreads();
    int ox = min(t, IMG-1);
    bool active = (t < IMG);
    const float4* xt = (const float4*)(tb + (size_t)ox*16);
    float4 cx0 = xt[0], cx1 = xt[1], sx0 = xt[2], sx1 = xt[3];
    const float4* av = (const float4*)(wsf + OFF_A + b*8);
    float4 a0 = av[0], a1 = av[1];
    float bias = 0.f;
    #pragma unroll
    for (int dd = 0; dd < 8; ++dd) bias += wsf[OFF_TERM + b*8 + dd];
    float mn = 1e30f, mx = -1e30f;
    #pragma unroll
    for (int rr = 0; rr < 7; ++rr) {
        const float* Y = lds_y + rr*16;
        float acc;
        acc  = (a0.x*Y[0])*cx0.x - (a0.x*Y[ 8])*sx0.x;
        acc += (a0.y*Y[1])*cx0.y - (a0.y*Y[ 9])*sx0.y;
        acc += (a0.z*Y[2])*cx0.z - (a0.z*Y[10])*sx0.z;
        acc += (a0.w*Y[3])*cx0.w - (a0.w*Y[11])*sx0.w;
        acc += (a1.x*Y[4])*cx1.x - (a1.x*Y[12])*sx1.x;
        acc += (a1.y*Y[5])*cx1.y - (a1.y*Y[13])*sx1.y;
        acc += (a1.z*Y[6])*cx1.z - (a1.z*Y[14])*sx1.z;
        acc += (a1.w*Y[7])*cx1.w - (a1.w*Y[15])*sx1.w;
        float g = acc - bias;
        if (active) {
            int oy = strip*7 + rr;
            wsf[OFF_G + ((size_t)(b*IMG + oy))*IMG + ox] = g;
            mn = fminf(mn, g);
            mx = fmaxf(mx, g);
        }
    }
    block_minmax_share<256>(mn, mx, red);
    if (t == 0) {
        wsf[OFF_GPMIN + blockIdx.x] = red[0];
        wsf[OFF_GPMAX + blockIdx.x] = red[1];
    }
}

/* K3: reduce 512 g-partials per block, normalize, 3-channel float4 write */
__global__ __launch_bounds__(256) void k_out(const float* __restrict__ wsf,
                                             float* __restrict__ out) {
    __shared__ float red[16];
    int t = threadIdx.x;
    float pmn = fminf(wsf[OFF_GPMIN + t], wsf[OFF_GPMIN + t + 256]);
    float pmx = fmaxf(wsf[OFF_GPMAX + t], wsf[OFF_GPMAX + t + 256]);
    block_minmax_share<256>(pmn, pmx, red);
    float gmin = red[0];
    float scale = 1.0f / ((red[1] - gmin) + 1e-6f);
    int idx = blockIdx.x*256 + t;                /* [0, 200704) float4 groups */
    float4 gv = ((const float4*)(wsf + OFF_G))[idx];
    float4 v;
    v.x = (gv.x - gmin)*scale;
    v.y = (gv.y - gmin)*scale;
    v.z = (gv.z - gmin)*scale;
    v.w = (gv.w - gmin)*scale;
    int b   = idx / (PIX/4);
    int rem = idx - b*(PIX/4);
    float4* ob = (float4*)(out + (size_t)b*3*PIX) + rem;
    ob[0]         = v;
    ob[PIX/4]     = v;
    ob[2*(PIX/4)] = v;
}

extern "C" void kernel_launch(void* const* d_in, const int* in_sizes, int n_in,
                              void* d_out, int out_size, void* d_ws, size_t ws_size,
                              hipStream_t stream) {
    const float* x = (const float*)d_in[0];
    float* out     = (float*)d_out;
    float* wsf     = (float*)d_ws;

    k_bd    <<<NBD,            1024, 0, stream>>>(x, wsf);
    k_resize<<<512,            256,  0, stream>>>(wsf);
    k_out   <<<(B_*PIX/4)/256, 256,  0, stream>>>(wsf, out);
}